// Round 1
// baseline (753.032 us; speedup 1.0000x reference)
//
#include <hip/hip_runtime.h>

#define NN 100000
#define DD 256
#define SCAN_BLK 1024

// ---------------- degree / norm ----------------
__global__ __launch_bounds__(256) void k_init_deg(int* __restrict__ dego,
                                                  int* __restrict__ degi) {
    int i = blockIdx.x * 256 + threadIdx.x;
    if (i < NN) { dego[i] = 1; degi[i] = 1; }  // self-loop contributes 1
}

__global__ __launch_bounds__(256) void k_count(const int* __restrict__ src,
                                               const int* __restrict__ dst, int E,
                                               int* __restrict__ dego,
                                               int* __restrict__ degi) {
    int e = blockIdx.x * 256 + threadIdx.x;
    if (e < E) {
        atomicAdd(&dego[src[e]], 1);
        atomicAdd(&degi[dst[e]], 1);
    }
}

__global__ __launch_bounds__(256) void k_norm(const int* __restrict__ dego,
                                              const int* __restrict__ degi,
                                              float* __restrict__ ns,
                                              float* __restrict__ nd) {
    int i = blockIdx.x * 256 + threadIdx.x;
    if (i < NN) {
        ns[i] = rsqrtf((float)dego[i]);
        nd[i] = rsqrtf((float)degi[i]);
    }
}

// ---------------- CSR build (scan by dst) ----------------
__device__ __forceinline__ int block_scan_inc(int v, int* sm) {
    int t = threadIdx.x;
    sm[t] = v;
    __syncthreads();
    for (int o = 1; o < SCAN_BLK; o <<= 1) {
        int x = (t >= o) ? sm[t - o] : 0;
        __syncthreads();
        sm[t] += x;
        __syncthreads();
    }
    return sm[t];
}

__global__ __launch_bounds__(SCAN_BLK) void k_scan1(const int* __restrict__ degi,
                                                    int* __restrict__ partials) {
    __shared__ int sm[SCAN_BLK];
    int i = blockIdx.x * SCAN_BLK + threadIdx.x;
    int v = (i < NN) ? (degi[i] - 1) : 0;  // real in-edges only (no self-loop)
    block_scan_inc(v, sm);
    if (threadIdx.x == 0) partials[blockIdx.x] = sm[SCAN_BLK - 1];
}

__global__ __launch_bounds__(128) void k_scan2(int* __restrict__ partials, int nb) {
    __shared__ int sm[128];
    int t = threadIdx.x;
    int v = (t < nb) ? partials[t] : 0;
    sm[t] = v;
    __syncthreads();
    for (int o = 1; o < 128; o <<= 1) {
        int x = (t >= o) ? sm[t - o] : 0;
        __syncthreads();
        sm[t] += x;
        __syncthreads();
    }
    if (t < nb) partials[t] = sm[t] - v;  // exclusive
}

__global__ __launch_bounds__(SCAN_BLK) void k_scan3(const int* __restrict__ degi,
                                                    const int* __restrict__ partials,
                                                    int* __restrict__ rowptr,
                                                    int* __restrict__ cursor) {
    __shared__ int sm[SCAN_BLK];
    int i = blockIdx.x * SCAN_BLK + threadIdx.x;
    int v = (i < NN) ? (degi[i] - 1) : 0;
    int incl = block_scan_inc(v, sm);
    int excl = partials[blockIdx.x] + incl - v;
    if (i <= NN) rowptr[i] = excl;   // rowptr[NN] = E
    if (i < NN) cursor[i] = excl;
}

__global__ __launch_bounds__(256) void k_fill(const int* __restrict__ src,
                                              const int* __restrict__ dst, int E,
                                              int* __restrict__ cursor,
                                              int* __restrict__ eidx) {
    int e = blockIdx.x * 256 + threadIdx.x;
    if (e < E) {
        int d = dst[e];
        int p = atomicAdd(&cursor[d], 1);
        eidx[p] = src[e];
    }
}

// ---------------- GEMM: out = (X * nrm_row) @ W  (fp32) ----------------
#define BM 64
#define BN 64
#define BK 16
__global__ __launch_bounds__(256) void k_gemm(const float* __restrict__ X,
                                              const float* __restrict__ nrm,
                                              const float* __restrict__ W,
                                              float* __restrict__ out) {
    __shared__ float xs[BK][BM + 4];  // transposed k-major, padded (16B-aligned rows)
    __shared__ float ws[BK][BN];
    int t = threadIdx.x;
    int brow = blockIdx.x * BM;
    int bcol = blockIdx.y * BN;
    int ty = t >> 4, tx = t & 15;
    int lr = t >> 2;            // 0..63 source row
    int lc = (t & 3) << 2;      // k offset 0,4,8,12
    int wr = t >> 4;            // 0..15 W row
    int wc = (t & 15) << 2;     // W col offset
    int grow = brow + lr;
    bool rv = (grow < NN);
    float nv = rv ? nrm[grow] : 0.0f;
    const float* xrow = X + (size_t)grow * DD;
    float acc[4][4] = {{0.f}};
    for (int k0 = 0; k0 < DD; k0 += BK) {
        float4 xv = make_float4(0.f, 0.f, 0.f, 0.f);
        if (rv) xv = *(const float4*)(xrow + k0 + lc);
        xs[lc + 0][lr] = xv.x * nv;
        xs[lc + 1][lr] = xv.y * nv;
        xs[lc + 2][lr] = xv.z * nv;
        xs[lc + 3][lr] = xv.w * nv;
        *(float4*)&ws[wr][wc] = *(const float4*)(W + (size_t)(k0 + wr) * DD + bcol + wc);
        __syncthreads();
#pragma unroll
        for (int kk = 0; kk < BK; ++kk) {
            float4 av = *(const float4*)&xs[kk][ty << 2];
            float4 bv = *(const float4*)&ws[kk][tx << 2];
            float a[4] = {av.x, av.y, av.z, av.w};
            float b[4] = {bv.x, bv.y, bv.z, bv.w};
#pragma unroll
            for (int i = 0; i < 4; i++)
#pragma unroll
                for (int j = 0; j < 4; j++)
                    acc[i][j] = fmaf(a[i], b[j], acc[i][j]);
        }
        __syncthreads();
    }
#pragma unroll
    for (int i = 0; i < 4; i++) {
        int r = brow + (ty << 2) + i;
        if (r < NN) {
            float4 o = make_float4(acc[i][0], acc[i][1], acc[i][2], acc[i][3]);
            *(float4*)(out + (size_t)r * DD + bcol + (tx << 2)) = o;
        }
    }
}

// ---------------- SpMM: one wave per dst node, regs accumulate ----------------
__global__ __launch_bounds__(256) void k_spmm(const float* __restrict__ T,
                                              const int* __restrict__ rowptr,
                                              const int* __restrict__ eidx,
                                              const float* __restrict__ nd,
                                              const float* __restrict__ bias,
                                              float* __restrict__ out, int relu) {
    int wid = threadIdx.x >> 6;
    int lane = threadIdx.x & 63;
    int node = blockIdx.x * 4 + wid;
    if (node >= NN) return;
    int c = lane << 2;
    float4 acc = *(const float4*)(T + (size_t)node * DD + c);  // self-loop
    int e = rowptr[node], end = rowptr[node + 1];
    for (; e < end; ++e) {
        int s = eidx[e];  // wave-uniform
        float4 v = *(const float4*)(T + (size_t)s * DD + c);
        acc.x += v.x; acc.y += v.y; acc.z += v.z; acc.w += v.w;
    }
    float n = nd[node];
    float4 bb = *(const float4*)(bias + c);
    float4 o;
    o.x = fmaf(acc.x, n, bb.x);
    o.y = fmaf(acc.y, n, bb.y);
    o.z = fmaf(acc.z, n, bb.z);
    o.w = fmaf(acc.w, n, bb.w);
    if (relu) {
        o.x = fmaxf(o.x, 0.f); o.y = fmaxf(o.y, 0.f);
        o.z = fmaxf(o.z, 0.f); o.w = fmaxf(o.w, 0.f);
    }
    *(float4*)(out + (size_t)node * DD + c) = o;
}

extern "C" void kernel_launch(void* const* d_in, const int* in_sizes, int n_in,
                              void* d_out, int out_size, void* d_ws, size_t ws_size,
                              hipStream_t stream) {
    const float* features = (const float*)d_in[0];
    const int* src = (const int*)d_in[1];
    const int* dst = (const int*)d_in[2];
    const float* W1 = (const float*)d_in[3];
    const float* b1 = (const float*)d_in[4];
    const float* W2 = (const float*)d_in[5];
    const float* b2 = (const float*)d_in[6];
    int E = in_sizes[1];
    float* out = (float*)d_out;

    size_t off = 0;
    auto alloc = [&](size_t nbytes) -> void* {
        void* p = (char*)d_ws + off;
        off += (nbytes + 255) & ~(size_t)255;
        return p;
    };
    int* dego = (int*)alloc((size_t)NN * 4);
    int* degi = (int*)alloc((size_t)NN * 4);
    float* norm_src = (float*)alloc((size_t)NN * 4);
    float* norm_dst = (float*)alloc((size_t)NN * 4);
    int* rowptr = (int*)alloc((size_t)(NN + 1) * 4);
    int* cursor = (int*)alloc((size_t)NN * 4);
    int* partials = (int*)alloc(128 * 4);
    int* eidx = (int*)alloc((size_t)E * 4);
    float* bufA = (float*)alloc((size_t)NN * DD * 4);
    // x1 is staged in d_out between the layers (re-written by the final SpMM).

    const int NB = (NN + SCAN_BLK - 1) / SCAN_BLK;  // 98

    k_init_deg<<<(NN + 255) / 256, 256, 0, stream>>>(dego, degi);
    k_count<<<(E + 255) / 256, 256, 0, stream>>>(src, dst, E, dego, degi);
    k_norm<<<(NN + 255) / 256, 256, 0, stream>>>(dego, degi, norm_src, norm_dst);
    k_scan1<<<NB, SCAN_BLK, 0, stream>>>(degi, partials);
    k_scan2<<<1, 128, 0, stream>>>(partials, NB);
    k_scan3<<<NB, SCAN_BLK, 0, stream>>>(degi, partials, rowptr, cursor);
    k_fill<<<(E + 255) / 256, 256, 0, stream>>>(src, dst, E, cursor, eidx);

    dim3 ggrid((NN + BM - 1) / BM, DD / BN);  // 1563 x 4
    // layer 1
    k_gemm<<<ggrid, 256, 0, stream>>>(features, norm_src, W1, bufA);
    k_spmm<<<(NN + 3) / 4, 256, 0, stream>>>(bufA, rowptr, eidx, norm_dst, b1, out, 1);
    // layer 2 (reads x1 from d_out, writes final into d_out)
    k_gemm<<<ggrid, 256, 0, stream>>>(out, norm_src, W2, bufA);
    k_spmm<<<(NN + 3) / 4, 256, 0, stream>>>(bufA, rowptr, eidx, norm_dst, b2, out, 0);
}

// Round 2
// 736.881 us; speedup vs baseline: 1.0219x; 1.0219x over previous
//
#include <hip/hip_runtime.h>

#define NN 100000
#define DD 256
#define SCAN_BLK 1024

// ---------------- degree / norm ----------------
__global__ __launch_bounds__(256) void k_init_deg(int* __restrict__ dego,
                                                  int* __restrict__ degi) {
    int i = blockIdx.x * 256 + threadIdx.x;
    if (i < NN) { dego[i] = 1; degi[i] = 1; }  // self-loop contributes 1
}

__global__ __launch_bounds__(256) void k_count(const int* __restrict__ src,
                                               const int* __restrict__ dst, int E,
                                               int* __restrict__ dego,
                                               int* __restrict__ degi) {
    int e = blockIdx.x * 256 + threadIdx.x;
    if (e < E) {
        atomicAdd(&dego[src[e]], 1);
        atomicAdd(&degi[dst[e]], 1);
    }
}

__global__ __launch_bounds__(256) void k_norm(const int* __restrict__ dego,
                                              const int* __restrict__ degi,
                                              float* __restrict__ ns,
                                              float* __restrict__ nd) {
    int i = blockIdx.x * 256 + threadIdx.x;
    if (i < NN) {
        ns[i] = rsqrtf((float)dego[i]);
        nd[i] = rsqrtf((float)degi[i]);
    }
}

// ---------------- CSR build (scan by dst) ----------------
__device__ __forceinline__ int block_scan_inc(int v, int* sm) {
    int t = threadIdx.x;
    sm[t] = v;
    __syncthreads();
    for (int o = 1; o < SCAN_BLK; o <<= 1) {
        int x = (t >= o) ? sm[t - o] : 0;
        __syncthreads();
        sm[t] += x;
        __syncthreads();
    }
    return sm[t];
}

__global__ __launch_bounds__(SCAN_BLK) void k_scan1(const int* __restrict__ degi,
                                                    int* __restrict__ partials) {
    __shared__ int sm[SCAN_BLK];
    int i = blockIdx.x * SCAN_BLK + threadIdx.x;
    int v = (i < NN) ? (degi[i] - 1) : 0;  // real in-edges only (no self-loop)
    block_scan_inc(v, sm);
    if (threadIdx.x == 0) partials[blockIdx.x] = sm[SCAN_BLK - 1];
}

__global__ __launch_bounds__(128) void k_scan2(int* __restrict__ partials, int nb) {
    __shared__ int sm[128];
    int t = threadIdx.x;
    int v = (t < nb) ? partials[t] : 0;
    sm[t] = v;
    __syncthreads();
    for (int o = 1; o < 128; o <<= 1) {
        int x = (t >= o) ? sm[t - o] : 0;
        __syncthreads();
        sm[t] += x;
        __syncthreads();
    }
    if (t < nb) partials[t] = sm[t] - v;  // exclusive
}

__global__ __launch_bounds__(SCAN_BLK) void k_scan3(const int* __restrict__ degi,
                                                    const int* __restrict__ partials,
                                                    int* __restrict__ rowptr,
                                                    int* __restrict__ cursor) {
    __shared__ int sm[SCAN_BLK];
    int i = blockIdx.x * SCAN_BLK + threadIdx.x;
    int v = (i < NN) ? (degi[i] - 1) : 0;
    int incl = block_scan_inc(v, sm);
    int excl = partials[blockIdx.x] + incl - v;
    if (i <= NN) rowptr[i] = excl;   // rowptr[NN] = E
    if (i < NN) cursor[i] = excl;
}

__global__ __launch_bounds__(256) void k_fill(const int* __restrict__ src,
                                              const int* __restrict__ dst, int E,
                                              int* __restrict__ cursor,
                                              int* __restrict__ eidx) {
    int e = blockIdx.x * 256 + threadIdx.x;
    if (e < E) {
        int d = dst[e];
        int p = atomicAdd(&cursor[d], 1);
        eidx[p] = src[e];
    }
}

// ---------------- GEMM: out = (X * nrm_row) @ W  (fp32) ----------------
// BM=64, BN=256(=D, X read once), BK=16, 8x8 register micro-tile split as
// 2x2 quadrants of 4x4 so all LDS reads are contiguous-b128 (conflict-free)
// and global stores are coalesced. 2 FLOP per LDS byte (vs 1 before).
#define BM 64
#define BK 16
#define XPAD 68   // 4*68 % 32banks = 16 -> 2-way alias on transpose store (free)
__global__ __launch_bounds__(256) void k_gemm(const float* __restrict__ X,
                                              const float* __restrict__ nrm,
                                              const float* __restrict__ W,
                                              float* __restrict__ out) {
    __shared__ float xs[BK][XPAD];     // k-major, transposed X tile (64 rows)
    __shared__ float ws[BK][DD];       // W tile, 16 x 256
    int t = threadIdx.x;
    int brow = blockIdx.x * BM;

    int rg = t >> 5;        // 0..7 : row group (rows rg*4..+3 and +32)
    int cg = t & 31;        // 0..31: col group (cols cg*4..+3 and +128)

    // X staging coords: one float4 per thread (64 rows x 16 cols)
    int xrow = t >> 2;      // 0..63
    int xcg = (t & 3) << 2; // k offset 0,4,8,12
    int grow = brow + xrow;
    bool rv = (grow < NN);
    float nv = rv ? nrm[grow] : 0.0f;
    const float* xrowp = X + (size_t)grow * DD;

    // W staging coords: four float4 per thread (16 rows x 256 cols)
    int wr0 = t >> 6;        // 0..3
    int wc = (t & 63) << 2;  // 0..252

    float acc[2][2][4][4] = {{{{0.f}}}};

    for (int k0 = 0; k0 < DD; k0 += BK) {
        float4 xv = make_float4(0.f, 0.f, 0.f, 0.f);
        if (rv) xv = *(const float4*)(xrowp + k0 + xcg);
        xs[xcg + 0][xrow] = xv.x * nv;
        xs[xcg + 1][xrow] = xv.y * nv;
        xs[xcg + 2][xrow] = xv.z * nv;
        xs[xcg + 3][xrow] = xv.w * nv;
#pragma unroll
        for (int i = 0; i < 4; ++i) {
            int wr = wr0 + (i << 2);
            *(float4*)&ws[wr][wc] = *(const float4*)(W + (size_t)(k0 + wr) * DD + wc);
        }
        __syncthreads();
#pragma unroll 4
        for (int kk = 0; kk < BK; ++kk) {
            float4 a0 = *(const float4*)&xs[kk][rg << 2];
            float4 a1 = *(const float4*)&xs[kk][(rg << 2) + 32];
            float4 b0 = *(const float4*)&ws[kk][cg << 2];
            float4 b1 = *(const float4*)&ws[kk][(cg << 2) + 128];
            float ar[2][4] = {{a0.x, a0.y, a0.z, a0.w}, {a1.x, a1.y, a1.z, a1.w}};
            float br[2][4] = {{b0.x, b0.y, b0.z, b0.w}, {b1.x, b1.y, b1.z, b1.w}};
#pragma unroll
            for (int ri = 0; ri < 2; ++ri)
#pragma unroll
                for (int ci = 0; ci < 2; ++ci)
#pragma unroll
                    for (int i = 0; i < 4; ++i)
#pragma unroll
                        for (int j = 0; j < 4; ++j)
                            acc[ri][ci][i][j] =
                                fmaf(ar[ri][i], br[ci][j], acc[ri][ci][i][j]);
        }
        __syncthreads();
    }

#pragma unroll
    for (int ri = 0; ri < 2; ++ri)
#pragma unroll
        for (int i = 0; i < 4; ++i) {
            int r = brow + (ri << 5) + (rg << 2) + i;
            if (r < NN) {
                float* op = out + (size_t)r * DD;
                *(float4*)(op + (cg << 2)) =
                    make_float4(acc[ri][0][i][0], acc[ri][0][i][1],
                                acc[ri][0][i][2], acc[ri][0][i][3]);
                *(float4*)(op + 128 + (cg << 2)) =
                    make_float4(acc[ri][1][i][0], acc[ri][1][i][1],
                                acc[ri][1][i][2], acc[ri][1][i][3]);
            }
        }
}

// ---------------- SpMM: one wave per dst node, regs accumulate ----------------
__global__ __launch_bounds__(256) void k_spmm(const float* __restrict__ T,
                                              const int* __restrict__ rowptr,
                                              const int* __restrict__ eidx,
                                              const float* __restrict__ nd,
                                              const float* __restrict__ bias,
                                              float* __restrict__ out, int relu) {
    int wid = threadIdx.x >> 6;
    int lane = threadIdx.x & 63;
    int node = blockIdx.x * 4 + wid;
    if (node >= NN) return;
    int c = lane << 2;
    float4 acc = *(const float4*)(T + (size_t)node * DD + c);  // self-loop
    float4 acc2 = make_float4(0.f, 0.f, 0.f, 0.f);
    int e = rowptr[node], end = rowptr[node + 1];
    for (; e + 1 < end; e += 2) {
        int s0 = eidx[e];
        int s1 = eidx[e + 1];
        float4 v0 = *(const float4*)(T + (size_t)s0 * DD + c);
        float4 v1 = *(const float4*)(T + (size_t)s1 * DD + c);
        acc.x += v0.x; acc.y += v0.y; acc.z += v0.z; acc.w += v0.w;
        acc2.x += v1.x; acc2.y += v1.y; acc2.z += v1.z; acc2.w += v1.w;
    }
    if (e < end) {
        int s = eidx[e];
        float4 v = *(const float4*)(T + (size_t)s * DD + c);
        acc.x += v.x; acc.y += v.y; acc.z += v.z; acc.w += v.w;
    }
    acc.x += acc2.x; acc.y += acc2.y; acc.z += acc2.z; acc.w += acc2.w;
    float n = nd[node];
    float4 bb = *(const float4*)(bias + c);
    float4 o;
    o.x = fmaf(acc.x, n, bb.x);
    o.y = fmaf(acc.y, n, bb.y);
    o.z = fmaf(acc.z, n, bb.z);
    o.w = fmaf(acc.w, n, bb.w);
    if (relu) {
        o.x = fmaxf(o.x, 0.f); o.y = fmaxf(o.y, 0.f);
        o.z = fmaxf(o.z, 0.f); o.w = fmaxf(o.w, 0.f);
    }
    *(float4*)(out + (size_t)node * DD + c) = o;
}

extern "C" void kernel_launch(void* const* d_in, const int* in_sizes, int n_in,
                              void* d_out, int out_size, void* d_ws, size_t ws_size,
                              hipStream_t stream) {
    const float* features = (const float*)d_in[0];
    const int* src = (const int*)d_in[1];
    const int* dst = (const int*)d_in[2];
    const float* W1 = (const float*)d_in[3];
    const float* b1 = (const float*)d_in[4];
    const float* W2 = (const float*)d_in[5];
    const float* b2 = (const float*)d_in[6];
    int E = in_sizes[1];
    float* out = (float*)d_out;

    size_t off = 0;
    auto alloc = [&](size_t nbytes) -> void* {
        void* p = (char*)d_ws + off;
        off += (nbytes + 255) & ~(size_t)255;
        return p;
    };
    int* dego = (int*)alloc((size_t)NN * 4);
    int* degi = (int*)alloc((size_t)NN * 4);
    float* norm_src = (float*)alloc((size_t)NN * 4);
    float* norm_dst = (float*)alloc((size_t)NN * 4);
    int* rowptr = (int*)alloc((size_t)(NN + 1) * 4);
    int* cursor = (int*)alloc((size_t)NN * 4);
    int* partials = (int*)alloc(128 * 4);
    int* eidx = (int*)alloc((size_t)E * 4);
    float* bufA = (float*)alloc((size_t)NN * DD * 4);
    // x1 is staged in d_out between the layers (re-written by the final SpMM).

    const int NB = (NN + SCAN_BLK - 1) / SCAN_BLK;  // 98

    k_init_deg<<<(NN + 255) / 256, 256, 0, stream>>>(dego, degi);
    k_count<<<(E + 255) / 256, 256, 0, stream>>>(src, dst, E, dego, degi);
    k_norm<<<(NN + 255) / 256, 256, 0, stream>>>(dego, degi, norm_src, norm_dst);
    k_scan1<<<NB, SCAN_BLK, 0, stream>>>(degi, partials);
    k_scan2<<<1, 128, 0, stream>>>(partials, NB);
    k_scan3<<<NB, SCAN_BLK, 0, stream>>>(degi, partials, rowptr, cursor);
    k_fill<<<(E + 255) / 256, 256, 0, stream>>>(src, dst, E, cursor, eidx);

    dim3 ggrid((NN + BM - 1) / BM);  // 1563, single column block (BN=256)
    // layer 1
    k_gemm<<<ggrid, 256, 0, stream>>>(features, norm_src, W1, bufA);
    k_spmm<<<(NN + 3) / 4, 256, 0, stream>>>(bufA, rowptr, eidx, norm_dst, b1, out, 1);
    // layer 2 (reads x1 from d_out, writes final into d_out)
    k_gemm<<<ggrid, 256, 0, stream>>>(out, norm_src, W2, bufA);
    k_spmm<<<(NN + 3) / 4, 256, 0, stream>>>(bufA, rowptr, eidx, norm_dst, b2, out, 0);
}

// Round 3
// 451.861 us; speedup vs baseline: 1.6665x; 1.6308x over previous
//
#include <hip/hip_runtime.h>

#define NN 100000
#define DD 256
#define SCAN_BLK 1024

typedef unsigned int uint;
typedef unsigned short ushort;
typedef __attribute__((ext_vector_type(8))) short bfx8;
typedef __attribute__((ext_vector_type(4))) float fx4;

__device__ __forceinline__ ushort f2bf(float f) {  // RNE
    uint u = __float_as_uint(f);
    u += 0x7fff + ((u >> 16) & 1);
    return (ushort)(u >> 16);
}

// ---------------- degree / norm ----------------
__global__ __launch_bounds__(256) void k_init_deg(int* __restrict__ dego,
                                                  int* __restrict__ degi) {
    int i = blockIdx.x * 256 + threadIdx.x;
    if (i < NN) { dego[i] = 1; degi[i] = 1; }  // self-loop contributes 1
}

__global__ __launch_bounds__(256) void k_count(const int* __restrict__ src,
                                               const int* __restrict__ dst, int E,
                                               int* __restrict__ dego,
                                               int* __restrict__ degi) {
    int e = blockIdx.x * 256 + threadIdx.x;
    if (e < E) {
        atomicAdd(&dego[src[e]], 1);
        atomicAdd(&degi[dst[e]], 1);
    }
}

__global__ __launch_bounds__(256) void k_norm(const int* __restrict__ dego,
                                              const int* __restrict__ degi,
                                              float* __restrict__ ns,
                                              float* __restrict__ nd) {
    int i = blockIdx.x * 256 + threadIdx.x;
    if (i < NN) {
        ns[i] = rsqrtf((float)dego[i]);
        nd[i] = rsqrtf((float)degi[i]);
    }
}

// ---------------- CSR build (scan by dst) ----------------
__device__ __forceinline__ int block_scan_inc(int v, int* sm) {
    int t = threadIdx.x;
    sm[t] = v;
    __syncthreads();
    for (int o = 1; o < SCAN_BLK; o <<= 1) {
        int x = (t >= o) ? sm[t - o] : 0;
        __syncthreads();
        sm[t] += x;
        __syncthreads();
    }
    return sm[t];
}

__global__ __launch_bounds__(SCAN_BLK) void k_scan1(const int* __restrict__ degi,
                                                    int* __restrict__ partials) {
    __shared__ int sm[SCAN_BLK];
    int i = blockIdx.x * SCAN_BLK + threadIdx.x;
    int v = (i < NN) ? (degi[i] - 1) : 0;  // real in-edges only
    block_scan_inc(v, sm);
    if (threadIdx.x == 0) partials[blockIdx.x] = sm[SCAN_BLK - 1];
}

__global__ __launch_bounds__(128) void k_scan2(int* __restrict__ partials, int nb) {
    __shared__ int sm[128];
    int t = threadIdx.x;
    int v = (t < nb) ? partials[t] : 0;
    sm[t] = v;
    __syncthreads();
    for (int o = 1; o < 128; o <<= 1) {
        int x = (t >= o) ? sm[t - o] : 0;
        __syncthreads();
        sm[t] += x;
        __syncthreads();
    }
    if (t < nb) partials[t] = sm[t] - v;  // exclusive
}

__global__ __launch_bounds__(SCAN_BLK) void k_scan3(const int* __restrict__ degi,
                                                    const int* __restrict__ partials,
                                                    int* __restrict__ rowptr,
                                                    int* __restrict__ cursor) {
    __shared__ int sm[SCAN_BLK];
    int i = blockIdx.x * SCAN_BLK + threadIdx.x;
    int v = (i < NN) ? (degi[i] - 1) : 0;
    int incl = block_scan_inc(v, sm);
    int excl = partials[blockIdx.x] + incl - v;
    if (i <= NN) rowptr[i] = excl;   // rowptr[NN] = E
    if (i < NN) cursor[i] = excl;
}

__global__ __launch_bounds__(256) void k_fill(const int* __restrict__ src,
                                              const int* __restrict__ dst, int E,
                                              int* __restrict__ cursor,
                                              int* __restrict__ eidx) {
    int e = blockIdx.x * 256 + threadIdx.x;
    if (e < E) {
        int d = dst[e];
        int p = atomicAdd(&cursor[d], 1);
        eidx[p] = src[e];
    }
}

// ---------------- conversions ----------------
// Wt[n][k] = bf16(W[k][n])  (transposed so GEMM B-frags read k-contiguous)
__global__ __launch_bounds__(256) void k_convW(const float* __restrict__ W,
                                               ushort* __restrict__ Wt) {
    int n = blockIdx.x, k = threadIdx.x;
    Wt[n * DD + k] = f2bf(W[(size_t)k * DD + n]);
}

// Xb[i][k] = bf16(X[i][k] * ns[i])
__global__ __launch_bounds__(256) void k_convX(const float* __restrict__ X,
                                               const float* __restrict__ ns,
                                               ushort* __restrict__ Xb) {
    int gid = blockIdx.x * 256 + threadIdx.x;  // one thread per 8 elements
    if (gid >= NN * DD / 8) return;
    int row = gid >> 5;
    int off = (gid & 31) << 3;
    float s = ns[row];
    const float4* p = (const float4*)(X + (size_t)row * DD + off);
    float4 a = p[0], b = p[1];
    union { ushort h[8]; uint4 v; } u;
    u.h[0] = f2bf(a.x * s); u.h[1] = f2bf(a.y * s);
    u.h[2] = f2bf(a.z * s); u.h[3] = f2bf(a.w * s);
    u.h[4] = f2bf(b.x * s); u.h[5] = f2bf(b.y * s);
    u.h[6] = f2bf(b.z * s); u.h[7] = f2bf(b.w * s);
    *(uint4*)(Xb + (size_t)gid * 8) = u.v;
}

// ---------------- MFMA GEMM: H = A @ Wt^T  (A: [NN][256] bf16 row-major,
// Wt: [256 n][256 k] bf16, H bf16). Tile 128x64, BK=64, 4 waves (2x2),
// wave tile 64x32 = 4x2 frags of 16x16. XOR-swizzled 16B chunks in LDS.
__global__ __launch_bounds__(256) void k_mfgemm(const ushort* __restrict__ A,
                                                const ushort* __restrict__ Wt,
                                                ushort* __restrict__ H) {
    __shared__ uint4 atq[2][128 * 8];  // A tile [128 r][8 chunks], dbuf, swizzled
    __shared__ uint4 wtq[64 * 32];     // Wt block [64 n][32 chunks], swizzled
    int t = threadIdx.x;
    int brow = blockIdx.x * 128;
    int bcol = blockIdx.y * 64;
    int lane = t & 63, w = t >> 6;
    int wr = w >> 1, wc = w & 1;       // wave grid 2x2
    int lg = lane >> 4, lr = lane & 15;

    // stage Wt block [bcol..bcol+63][0..255] (persistent, 32 KB)
    {
        const uint4* src = (const uint4*)Wt + (size_t)bcol * 32;
#pragma unroll
        for (int i = 0; i < 8; ++i) {
            int q = i * 256 + t;          // 0..2047
            int n = q >> 5, c = q & 31;
            wtq[n * 32 + (c ^ (n & 7))] = src[q];
        }
    }

    fx4 acc[4][2];
#pragma unroll
    for (int mi = 0; mi < 4; ++mi)
#pragma unroll
        for (int ni = 0; ni < 2; ++ni)
            acc[mi][ni] = (fx4){0.f, 0.f, 0.f, 0.f};

    // A staging helpers: 1024 chunks of 16B per K-step
    int q0 = t;                      // chunk ids t, t+256, t+512, t+768
    int sr0 = q0 >> 3, sc0 = q0 & 7; // row/chunk within tile (row += 32/iter)
    auto ldA = [&](uint4* sv, int ks) {
#pragma unroll
        for (int i = 0; i < 4; ++i) {
            int r = sr0 + i * 32;
            int row = brow + r; if (row >= NN) row = NN - 1;  // tail clamp
            sv[i] = *(const uint4*)(A + (size_t)row * DD + ks * 64 + sc0 * 8);
        }
    };
    auto wrA = [&](int buf, const uint4* sv) {
#pragma unroll
        for (int i = 0; i < 4; ++i) {
            int r = sr0 + i * 32;
            atq[buf][r * 8 + (sc0 ^ (r & 7))] = sv[i];
        }
    };

    uint4 sv[4];
    ldA(sv, 0);
    wrA(0, sv);
    __syncthreads();

    int buf = 0;
    for (int ks = 0; ks < 4; ++ks) {
        if (ks < 3) ldA(sv, ks + 1);          // issue early (hide under MFMA)
#pragma unroll
        for (int kk = 0; kk < 2; ++kk) {
            bfx8 af[4], bfr[2];
#pragma unroll
            for (int mi = 0; mi < 4; ++mi) {
                int r = wr * 64 + mi * 16 + lr;
                int c = kk * 4 + lg;
                af[mi] = *(const bfx8*)&atq[buf][r * 8 + (c ^ (r & 7))];
            }
#pragma unroll
            for (int ni = 0; ni < 2; ++ni) {
                int n = wc * 32 + ni * 16 + lr;
                int c = ks * 8 + kk * 4 + lg;
                bfr[ni] = *(const bfx8*)&wtq[n * 32 + (c ^ (n & 7))];
            }
#pragma unroll
            for (int mi = 0; mi < 4; ++mi)
#pragma unroll
                for (int ni = 0; ni < 2; ++ni)
                    acc[mi][ni] = __builtin_amdgcn_mfma_f32_16x16x32_bf16(
                        af[mi], bfr[ni], acc[mi][ni], 0, 0, 0);
        }
        if (ks < 3) wrA(buf ^ 1, sv);         // write late
        __syncthreads();
        buf ^= 1;
    }

    // epilogue: C/D layout col=lane&15, row=(lane>>4)*4+reg (verified m89/m91)
#pragma unroll
    for (int mi = 0; mi < 4; ++mi) {
        int rbase = brow + wr * 64 + mi * 16 + lg * 4;
#pragma unroll
        for (int ni = 0; ni < 2; ++ni) {
            int col = bcol + wc * 32 + ni * 16 + lr;
#pragma unroll
            for (int j = 0; j < 4; ++j) {
                int row = rbase + j;
                if (row < NN)
                    H[(size_t)row * DD + col] = f2bf(acc[mi][ni][j]);
            }
        }
    }
}

// ---------------- SpMM (bf16 gather, fp32 accum): one wave per dst node ----
// layer1: obf = bf16(relu(agg*nd + b) * ns)   (pre-scaled next-GEMM input)
// layer2: of  = agg*nd + b                     (final fp32 output)
__global__ __launch_bounds__(256) void k_spmm_bf(const ushort* __restrict__ T,
                                                 const int* __restrict__ rowptr,
                                                 const int* __restrict__ eidx,
                                                 const float* __restrict__ nd,
                                                 const float* __restrict__ ns,
                                                 const float* __restrict__ bias,
                                                 ushort* __restrict__ obf,
                                                 float* __restrict__ of,
                                                 int layer1) {
    int wid = threadIdx.x >> 6, lane = threadIdx.x & 63;
    int node = blockIdx.x * 4 + wid;
    if (node >= NN) return;
    int c = lane << 2;  // 4 bf16 per lane
    uint2 sv = *(const uint2*)(T + (size_t)node * DD + c);  // self-loop
    float a0 = __uint_as_float(sv.x << 16);
    float a1 = __uint_as_float(sv.x & 0xffff0000u);
    float a2 = __uint_as_float(sv.y << 16);
    float a3 = __uint_as_float(sv.y & 0xffff0000u);
    float b0 = 0.f, b1 = 0.f, b2 = 0.f, b3 = 0.f;
    int e = rowptr[node], end = rowptr[node + 1];
    for (; e + 1 < end; e += 2) {
        int s0 = eidx[e], s1 = eidx[e + 1];
        uint2 v0 = *(const uint2*)(T + (size_t)s0 * DD + c);
        uint2 v1 = *(const uint2*)(T + (size_t)s1 * DD + c);
        a0 += __uint_as_float(v0.x << 16);
        a1 += __uint_as_float(v0.x & 0xffff0000u);
        a2 += __uint_as_float(v0.y << 16);
        a3 += __uint_as_float(v0.y & 0xffff0000u);
        b0 += __uint_as_float(v1.x << 16);
        b1 += __uint_as_float(v1.x & 0xffff0000u);
        b2 += __uint_as_float(v1.y << 16);
        b3 += __uint_as_float(v1.y & 0xffff0000u);
    }
    if (e < end) {
        int s0 = eidx[e];
        uint2 v0 = *(const uint2*)(T + (size_t)s0 * DD + c);
        a0 += __uint_as_float(v0.x << 16);
        a1 += __uint_as_float(v0.x & 0xffff0000u);
        a2 += __uint_as_float(v0.y << 16);
        a3 += __uint_as_float(v0.y & 0xffff0000u);
    }
    a0 += b0; a1 += b1; a2 += b2; a3 += b3;
    float n = nd[node];
    float4 bb = *(const float4*)(bias + c);
    float o0 = fmaf(a0, n, bb.x);
    float o1 = fmaf(a1, n, bb.y);
    float o2 = fmaf(a2, n, bb.z);
    float o3 = fmaf(a3, n, bb.w);
    if (layer1) {
        float s = ns[node];
        o0 = fmaxf(o0, 0.f) * s; o1 = fmaxf(o1, 0.f) * s;
        o2 = fmaxf(o2, 0.f) * s; o3 = fmaxf(o3, 0.f) * s;
        uint lo = (uint)f2bf(o0) | ((uint)f2bf(o1) << 16);
        uint hi = (uint)f2bf(o2) | ((uint)f2bf(o3) << 16);
        *(uint2*)(obf + (size_t)node * DD + c) = make_uint2(lo, hi);
    } else {
        *(float4*)(of + (size_t)node * DD + c) = make_float4(o0, o1, o2, o3);
    }
}

extern "C" void kernel_launch(void* const* d_in, const int* in_sizes, int n_in,
                              void* d_out, int out_size, void* d_ws, size_t ws_size,
                              hipStream_t stream) {
    const float* features = (const float*)d_in[0];
    const int* src = (const int*)d_in[1];
    const int* dst = (const int*)d_in[2];
    const float* W1 = (const float*)d_in[3];
    const float* b1 = (const float*)d_in[4];
    const float* W2 = (const float*)d_in[5];
    const float* b2 = (const float*)d_in[6];
    int E = in_sizes[1];
    float* out = (float*)d_out;

    size_t off = 0;
    auto alloc = [&](size_t nbytes) -> void* {
        void* p = (char*)d_ws + off;
        off += (nbytes + 255) & ~(size_t)255;
        return p;
    };
    int* dego = (int*)alloc((size_t)NN * 4);
    int* degi = (int*)alloc((size_t)NN * 4);
    float* norm_src = (float*)alloc((size_t)NN * 4);
    float* norm_dst = (float*)alloc((size_t)NN * 4);
    int* rowptr = (int*)alloc((size_t)(NN + 1) * 4);
    int* cursor = (int*)alloc((size_t)NN * 4);
    int* partials = (int*)alloc(128 * 4);
    int* eidx = (int*)alloc((size_t)E * 4);
    ushort* Wt1 = (ushort*)alloc((size_t)DD * DD * 2);
    ushort* Wt2 = (ushort*)alloc((size_t)DD * DD * 2);
    ushort* Xbf = (ushort*)alloc((size_t)NN * DD * 2);
    ushort* Hbf = (ushort*)alloc((size_t)NN * DD * 2);

    const int NB = (NN + SCAN_BLK - 1) / SCAN_BLK;  // 98

    k_init_deg<<<(NN + 255) / 256, 256, 0, stream>>>(dego, degi);
    k_count<<<(E + 255) / 256, 256, 0, stream>>>(src, dst, E, dego, degi);
    k_norm<<<(NN + 255) / 256, 256, 0, stream>>>(dego, degi, norm_src, norm_dst);
    k_scan1<<<NB, SCAN_BLK, 0, stream>>>(degi, partials);
    k_scan2<<<1, 128, 0, stream>>>(partials, NB);
    k_scan3<<<NB, SCAN_BLK, 0, stream>>>(degi, partials, rowptr, cursor);
    k_fill<<<(E + 255) / 256, 256, 0, stream>>>(src, dst, E, cursor, eidx);

    k_convW<<<DD, DD, 0, stream>>>(W1, Wt1);
    k_convW<<<DD, DD, 0, stream>>>(W2, Wt2);
    k_convX<<<(NN * DD / 8 + 255) / 256, 256, 0, stream>>>(features, norm_src, Xbf);

    dim3 ggrid((NN + 127) / 128, 4);  // 782 x 4
    // layer 1
    k_mfgemm<<<ggrid, 256, 0, stream>>>(Xbf, Wt1, Hbf);
    k_spmm_bf<<<(NN + 3) / 4, 256, 0, stream>>>(Hbf, rowptr, eidx, norm_dst,
                                                norm_src, b1, Xbf, out, 1);
    // layer 2
    k_mfgemm<<<ggrid, 256, 0, stream>>>(Xbf, Wt2, Hbf);
    k_spmm_bf<<<(NN + 3) / 4, 256, 0, stream>>>(Hbf, rowptr, eidx, norm_dst,
                                                norm_src, b2, nullptr, out, 0);
}

// Round 5
// 384.851 us; speedup vs baseline: 1.9567x; 1.1741x over previous
//
#include <hip/hip_runtime.h>

#define NN 100000
#define DD 256
#define SCAN_BLK 1024

typedef unsigned int uint;
typedef unsigned short ushort;
typedef __attribute__((ext_vector_type(8))) short bfx8;
typedef __attribute__((ext_vector_type(4))) float fx4;

__device__ __forceinline__ ushort f2bf(float f) {  // RNE
    uint u = __float_as_uint(f);
    u += 0x7fff + ((u >> 16) & 1);
    return (ushort)(u >> 16);
}

// ---------------- degree / norm ----------------
__global__ __launch_bounds__(256) void k_init_deg(int* __restrict__ dego,
                                                  int* __restrict__ degi) {
    int i = blockIdx.x * 256 + threadIdx.x;
    if (i < NN) { dego[i] = 1; degi[i] = 1; }  // self-loop contributes 1
}

__global__ __launch_bounds__(256) void k_count(const int* __restrict__ src,
                                               const int* __restrict__ dst, int E,
                                               int* __restrict__ dego,
                                               int* __restrict__ degi) {
    int e = blockIdx.x * 256 + threadIdx.x;
    if (e < E) {
        atomicAdd(&dego[src[e]], 1);
        atomicAdd(&degi[dst[e]], 1);
    }
}

__global__ __launch_bounds__(256) void k_norm(const int* __restrict__ dego,
                                              const int* __restrict__ degi,
                                              float* __restrict__ ns,
                                              float* __restrict__ nd) {
    int i = blockIdx.x * 256 + threadIdx.x;
    if (i < NN) {
        ns[i] = rsqrtf((float)dego[i]);
        nd[i] = rsqrtf((float)degi[i]);
    }
}

// ---------------- CSR build (scan by dst) ----------------
__device__ __forceinline__ int block_scan_inc(int v, int* sm) {
    int t = threadIdx.x;
    sm[t] = v;
    __syncthreads();
    for (int o = 1; o < SCAN_BLK; o <<= 1) {
        int x = (t >= o) ? sm[t - o] : 0;
        __syncthreads();
        sm[t] += x;
        __syncthreads();
    }
    return sm[t];
}

__global__ __launch_bounds__(SCAN_BLK) void k_scan1(const int* __restrict__ degi,
                                                    int* __restrict__ partials) {
    __shared__ int sm[SCAN_BLK];
    int i = blockIdx.x * SCAN_BLK + threadIdx.x;
    int v = (i < NN) ? (degi[i] - 1) : 0;  // real in-edges only
    block_scan_inc(v, sm);
    if (threadIdx.x == 0) partials[blockIdx.x] = sm[SCAN_BLK - 1];
}

__global__ __launch_bounds__(128) void k_scan2(int* __restrict__ partials, int nb) {
    __shared__ int sm[128];
    int t = threadIdx.x;
    int v = (t < nb) ? partials[t] : 0;
    sm[t] = v;
    __syncthreads();
    for (int o = 1; o < 128; o <<= 1) {
        int x = (t >= o) ? sm[t - o] : 0;
        __syncthreads();
        sm[t] += x;
        __syncthreads();
    }
    if (t < nb) partials[t] = sm[t] - v;  // exclusive
}

__global__ __launch_bounds__(SCAN_BLK) void k_scan3(const int* __restrict__ degi,
                                                    const int* __restrict__ partials,
                                                    int* __restrict__ rowptr,
                                                    int* __restrict__ cursor) {
    __shared__ int sm[SCAN_BLK];
    int i = blockIdx.x * SCAN_BLK + threadIdx.x;
    int v = (i < NN) ? (degi[i] - 1) : 0;
    int incl = block_scan_inc(v, sm);
    int excl = partials[blockIdx.x] + incl - v;
    if (i <= NN) rowptr[i] = excl;   // rowptr[NN] = E
    if (i < NN) cursor[i] = excl;
}

__global__ __launch_bounds__(256) void k_fill(const int* __restrict__ src,
                                              const int* __restrict__ dst, int E,
                                              int* __restrict__ cursor,
                                              int* __restrict__ eidx) {
    int e = blockIdx.x * 256 + threadIdx.x;
    if (e < E) {
        int d = dst[e];
        int p = atomicAdd(&cursor[d], 1);
        eidx[p] = src[e];
    }
}

// Wt[n][k] = bf16(W[k][n])  (transposed so GEMM B-frags read k-contiguous)
__global__ __launch_bounds__(256) void k_convW(const float* __restrict__ W,
                                               ushort* __restrict__ Wt) {
    int n = blockIdx.x, k = threadIdx.x;
    Wt[n * DD + k] = f2bf(W[(size_t)k * DD + n]);
}

// ---------------- MFMA GEMM: H = A @ Wt^T ----------------
// Tile 256x128, BK=64, 512 threads (8 waves, 4x2), wave tile 64x64 (4x4 frags
// of 16x16x32). LDS: A dbuf 64 KB + Wt panel 64 KB = 128 KB. XOR-swizzled
// 16B chunks (same verified scheme as round 3). FP32A=true reads fp32 A and
// applies per-row scale nrm while converting to bf16 in-register (fuses the
// old convX pass into layer-1 staging).
template <bool FP32A>
__global__ __launch_bounds__(512) void k_mfgemm(const void* __restrict__ Av,
                                                const float* __restrict__ nrm,
                                                const ushort* __restrict__ Wt,
                                                ushort* __restrict__ H) {
    __shared__ uint4 atq[2][256 * 8];  // A tile [256 r][8 chunks], dbuf, swizzled
    __shared__ uint4 wtq[128 * 32];    // Wt panel [128 n][32 chunks], swizzled
    int t = threadIdx.x;
    int brow = blockIdx.x * 256;
    int bcol = blockIdx.y * 128;
    int lane = t & 63, w = t >> 6;
    int wr = w >> 1, wc = w & 1;       // wave grid 4x2
    int lg = lane >> 4, lr = lane & 15;

    // stage Wt panel [bcol..bcol+127][0..255] (persistent, 64 KB)
    {
        const uint4* srcp = (const uint4*)Wt + (size_t)bcol * 32;
#pragma unroll
        for (int i = 0; i < 8; ++i) {
            int q = i * 512 + t;          // 0..4095
            int n = q >> 5, c = q & 31;
            wtq[n * 32 + (c ^ (n & 7))] = srcp[q];
        }
    }

    int sr0 = t >> 3, sc0 = t & 7;  // staging row 0..63 (+i*64), chunk 0..7
    int rows_[4];
    float ns_[4];
#pragma unroll
    for (int i = 0; i < 4; ++i) {
        int r = brow + sr0 + i * 64;
        if (r >= NN) r = NN - 1;  // tail clamp (results discarded on store)
        rows_[i] = r;
        if (FP32A) ns_[i] = nrm[r];
    }

    fx4 acc[4][4];
#pragma unroll
    for (int mi = 0; mi < 4; ++mi)
#pragma unroll
        for (int ni = 0; ni < 4; ++ni)
            acc[mi][ni] = (fx4){0.f, 0.f, 0.f, 0.f};

    uint4 sv[4];
    float4 svf[4][2];

    auto ldA = [&](int ks) {
        if (FP32A) {
            const float* X = (const float*)Av;
#pragma unroll
            for (int i = 0; i < 4; ++i) {
                const float4* p =
                    (const float4*)(X + (size_t)rows_[i] * DD + ks * 64 + sc0 * 8);
                svf[i][0] = p[0];
                svf[i][1] = p[1];
            }
        } else {
            const ushort* A = (const ushort*)Av;
#pragma unroll
            for (int i = 0; i < 4; ++i)
                sv[i] = *(const uint4*)(A + (size_t)rows_[i] * DD + ks * 64 + sc0 * 8);
        }
    };
    auto wrA = [&](int buf) {
#pragma unroll
        for (int i = 0; i < 4; ++i) {
            int r = sr0 + i * 64;
            uint4 u;
            if (FP32A) {
                float s = ns_[i];
                float4 a = svf[i][0], b = svf[i][1];
                u.x = (uint)f2bf(a.x * s) | ((uint)f2bf(a.y * s) << 16);
                u.y = (uint)f2bf(a.z * s) | ((uint)f2bf(a.w * s) << 16);
                u.z = (uint)f2bf(b.x * s) | ((uint)f2bf(b.y * s) << 16);
                u.w = (uint)f2bf(b.z * s) | ((uint)f2bf(b.w * s) << 16);
            } else {
                u = sv[i];
            }
            atq[buf][r * 8 + (sc0 ^ (r & 7))] = u;
        }
    };

    ldA(0);
    wrA(0);
    __syncthreads();

    int buf = 0;
    for (int ks = 0; ks < 4; ++ks) {
        if (ks < 3) ldA(ks + 1);  // issue early: HBM latency hides under MFMA
#pragma unroll
        for (int kk = 0; kk < 2; ++kk) {
            bfx8 af[4], bfr[4];
#pragma unroll
            for (int mi = 0; mi < 4; ++mi) {
                int r = wr * 64 + mi * 16 + lr;
                int c = kk * 4 + lg;
                af[mi] = *(const bfx8*)&atq[buf][r * 8 + (c ^ (r & 7))];
            }
#pragma unroll
            for (int ni = 0; ni < 4; ++ni) {
                int n = wc * 64 + ni * 16 + lr;
                int c2 = ks * 8 + kk * 4 + lg;
                bfr[ni] = *(const bfx8*)&wtq[n * 32 + (c2 ^ (n & 7))];
            }
#pragma unroll
            for (int mi = 0; mi < 4; ++mi)
#pragma unroll
                for (int ni = 0; ni < 4; ++ni)
                    acc[mi][ni] = __builtin_amdgcn_mfma_f32_16x16x32_bf16(
                        af[mi], bfr[ni], acc[mi][ni], 0, 0, 0);
        }
        if (ks < 3) wrA(buf ^ 1);  // write late, into the other buffer
        __syncthreads();
        buf ^= 1;
    }

    // epilogue: C/D layout col=lane&15, row=(lane>>4)*4+reg (verified m89/m91)
#pragma unroll
    for (int mi = 0; mi < 4; ++mi) {
        int rbase = brow + wr * 64 + mi * 16 + lg * 4;
#pragma unroll
        for (int ni = 0; ni < 4; ++ni) {
            int col = bcol + wc * 64 + ni * 16 + lr;
#pragma unroll
            for (int j = 0; j < 4; ++j) {
                int row = rbase + j;
                if (row < NN) H[(size_t)row * DD + col] = f2bf(acc[mi][ni][j]);
            }
        }
    }
}

// ---------------- SpMM (bf16 gather, fp32 accum): one wave per dst node ----
// layer1: obf = bf16(relu(agg*nd + b) * ns)   (pre-scaled next-GEMM input)
// layer2: of  = agg*nd + b (final fp32, nontemporal store: write-once data,
//               keep it from evicting the gather working set)
__global__ __launch_bounds__(256) void k_spmm_bf(const ushort* __restrict__ T,
                                                 const int* __restrict__ rowptr,
                                                 const int* __restrict__ eidx,
                                                 const float* __restrict__ nd,
                                                 const float* __restrict__ ns,
                                                 const float* __restrict__ bias,
                                                 ushort* __restrict__ obf,
                                                 float* __restrict__ of,
                                                 int layer1) {
    int wid = threadIdx.x >> 6, lane = threadIdx.x & 63;
    int node = blockIdx.x * 4 + wid;
    if (node >= NN) return;
    int c = lane << 2;  // 4 bf16 per lane
    uint2 sv = *(const uint2*)(T + (size_t)node * DD + c);  // self-loop
    float p0[4], p1[4], p2[4], p3[4];
    p0[0] = __uint_as_float(sv.x << 16);
    p0[1] = __uint_as_float(sv.x & 0xffff0000u);
    p0[2] = __uint_as_float(sv.y << 16);
    p0[3] = __uint_as_float(sv.y & 0xffff0000u);
#pragma unroll
    for (int j = 0; j < 4; ++j) { p1[j] = 0.f; p2[j] = 0.f; p3[j] = 0.f; }
    int e = rowptr[node], end = rowptr[node + 1];
    for (; e + 3 < end; e += 4) {
        int s0 = eidx[e], s1 = eidx[e + 1], s2 = eidx[e + 2], s3 = eidx[e + 3];
        uint2 v0 = *(const uint2*)(T + (size_t)s0 * DD + c);
        uint2 v1 = *(const uint2*)(T + (size_t)s1 * DD + c);
        uint2 v2 = *(const uint2*)(T + (size_t)s2 * DD + c);
        uint2 v3 = *(const uint2*)(T + (size_t)s3 * DD + c);
        p0[0] += __uint_as_float(v0.x << 16);
        p0[1] += __uint_as_float(v0.x & 0xffff0000u);
        p0[2] += __uint_as_float(v0.y << 16);
        p0[3] += __uint_as_float(v0.y & 0xffff0000u);
        p1[0] += __uint_as_float(v1.x << 16);
        p1[1] += __uint_as_float(v1.x & 0xffff0000u);
        p1[2] += __uint_as_float(v1.y << 16);
        p1[3] += __uint_as_float(v1.y & 0xffff0000u);
        p2[0] += __uint_as_float(v2.x << 16);
        p2[1] += __uint_as_float(v2.x & 0xffff0000u);
        p2[2] += __uint_as_float(v2.y << 16);
        p2[3] += __uint_as_float(v2.y & 0xffff0000u);
        p3[0] += __uint_as_float(v3.x << 16);
        p3[1] += __uint_as_float(v3.x & 0xffff0000u);
        p3[2] += __uint_as_float(v3.y << 16);
        p3[3] += __uint_as_float(v3.y & 0xffff0000u);
    }
    for (; e < end; ++e) {
        int s0 = eidx[e];
        uint2 v0 = *(const uint2*)(T + (size_t)s0 * DD + c);
        p0[0] += __uint_as_float(v0.x << 16);
        p0[1] += __uint_as_float(v0.x & 0xffff0000u);
        p0[2] += __uint_as_float(v0.y << 16);
        p0[3] += __uint_as_float(v0.y & 0xffff0000u);
    }
#pragma unroll
    for (int j = 0; j < 4; ++j) p0[j] += (p1[j] + p2[j]) + p3[j];
    float n = nd[node];
    float4 bb = *(const float4*)(bias + c);
    float o0 = fmaf(p0[0], n, bb.x);
    float o1 = fmaf(p0[1], n, bb.y);
    float o2 = fmaf(p0[2], n, bb.z);
    float o3 = fmaf(p0[3], n, bb.w);
    if (layer1) {
        float s = ns[node];
        o0 = fmaxf(o0, 0.f) * s; o1 = fmaxf(o1, 0.f) * s;
        o2 = fmaxf(o2, 0.f) * s; o3 = fmaxf(o3, 0.f) * s;
        uint lo = (uint)f2bf(o0) | ((uint)f2bf(o1) << 16);
        uint hi = (uint)f2bf(o2) | ((uint)f2bf(o3) << 16);
        *(uint2*)(obf + (size_t)node * DD + c) = make_uint2(lo, hi);
    } else {
        fx4 o = {o0, o1, o2, o3};
        __builtin_nontemporal_store(o, (fx4*)(of + (size_t)node * DD + c));
    }
}

extern "C" void kernel_launch(void* const* d_in, const int* in_sizes, int n_in,
                              void* d_out, int out_size, void* d_ws, size_t ws_size,
                              hipStream_t stream) {
    const float* features = (const float*)d_in[0];
    const int* src = (const int*)d_in[1];
    const int* dst = (const int*)d_in[2];
    const float* W1 = (const float*)d_in[3];
    const float* b1 = (const float*)d_in[4];
    const float* W2 = (const float*)d_in[5];
    const float* b2 = (const float*)d_in[6];
    int E = in_sizes[1];
    float* out = (float*)d_out;

    size_t off = 0;
    auto alloc = [&](size_t nbytes) -> void* {
        void* p = (char*)d_ws + off;
        off += (nbytes + 255) & ~(size_t)255;
        return p;
    };
    int* dego = (int*)alloc((size_t)NN * 4);
    int* degi = (int*)alloc((size_t)NN * 4);
    float* norm_src = (float*)alloc((size_t)NN * 4);
    float* norm_dst = (float*)alloc((size_t)NN * 4);
    int* rowptr = (int*)alloc((size_t)(NN + 1) * 4);
    int* cursor = (int*)alloc((size_t)NN * 4);
    int* partials = (int*)alloc(128 * 4);
    int* eidx = (int*)alloc((size_t)E * 4);
    ushort* Wt1 = (ushort*)alloc((size_t)DD * DD * 2);
    ushort* Wt2 = (ushort*)alloc((size_t)DD * DD * 2);
    ushort* Xbf = (ushort*)alloc((size_t)NN * DD * 2);
    ushort* Hbf = (ushort*)alloc((size_t)NN * DD * 2);

    const int NB = (NN + SCAN_BLK - 1) / SCAN_BLK;  // 98

    k_init_deg<<<(NN + 255) / 256, 256, 0, stream>>>(dego, degi);
    k_count<<<(E + 255) / 256, 256, 0, stream>>>(src, dst, E, dego, degi);
    k_norm<<<(NN + 255) / 256, 256, 0, stream>>>(dego, degi, norm_src, norm_dst);
    k_scan1<<<NB, SCAN_BLK, 0, stream>>>(degi, partials);
    k_scan2<<<1, 128, 0, stream>>>(partials, NB);
    k_scan3<<<NB, SCAN_BLK, 0, stream>>>(degi, partials, rowptr, cursor);
    k_fill<<<(E + 255) / 256, 256, 0, stream>>>(src, dst, E, cursor, eidx);

    k_convW<<<DD, DD, 0, stream>>>(W1, Wt1);
    k_convW<<<DD, DD, 0, stream>>>(W2, Wt2);

    dim3 ggrid((NN + 255) / 256, 2);  // 391 x 2
    // layer 1 (GEMM reads fp32 features, scales by norm_src while staging)
    k_mfgemm<true><<<ggrid, 512, 0, stream>>>(features, norm_src, Wt1, Hbf);
    k_spmm_bf<<<(NN + 3) / 4, 256, 0, stream>>>(Hbf, rowptr, eidx, norm_dst,
                                                norm_src, b1, Xbf, out, 1);
    // layer 2
    k_mfgemm<false><<<ggrid, 512, 0, stream>>>(Xbf, nullptr, Wt2, Hbf);
    k_spmm_bf<<<(NN + 3) / 4, 256, 0, stream>>>(Hbf, rowptr, eidx, norm_dst,
                                                norm_src, b2, nullptr, out, 0);
}